// Round 2
// baseline (31072.290 us; speedup 1.0000x reference)
//
#include <hip/hip_runtime.h>
#include <cstdint>
#include <cstddef>

#define T_SEQ 2048
#define BATCH 16
#define DIM   512
#define HID   512
#define KTOT  1024            // D + H
#define NCOL  2048            // 4H per direction
#define APAD  8
#define AROW  (KTOT + APAD)   // 1032 bf16 elems per A row

typedef __attribute__((ext_vector_type(8))) short          s8v;
typedef __attribute__((ext_vector_type(4))) float          f4v;
typedef __attribute__((ext_vector_type(4))) unsigned short h4v;

__device__ __forceinline__ unsigned short f2b(float f) {
  unsigned u = __builtin_bit_cast(unsigned, f);
  return (unsigned short)((u + 0x7fffu + ((u >> 16) & 1u)) >> 16);  // RNE
}

__device__ __forceinline__ f4v mfma16(s8v a, s8v b, f4v c) {
  return __builtin_amdgcn_mfma_f32_16x16x32_bf16(a, b, c, 0, 0, 0);
}

// grid = 64 wgs x 256 thr. wg w: dir = w>>5, j-block = (w&31)*16.
// wave wv (0..3) owns gate wv's 16 cols; W fragments persist in 128 VGPRs.
// h is exchanged through d_out (fwd: row t-1; bwd: row (tau+1)%T), so d_ws
// holds ONLY the two barrier counters.
__global__ __launch_bounds__(256, 1)
void lstm_persist(const float* __restrict__ x, const int* __restrict__ lengths,
                  const float* __restrict__ Wi_f, const float* __restrict__ Wh_f,
                  const float* __restrict__ b_f,
                  const float* __restrict__ Wi_b, const float* __restrict__ Wh_b,
                  const float* __restrict__ b_b,
                  unsigned int* __restrict__ ctr,
                  float* __restrict__ out) {
  __shared__ unsigned short A[BATCH][AROW];   // [b][k] bf16, +8 pad
  __shared__ float glds[4][BATCH][16];        // gate exchange

  const int w    = (int)blockIdx.x;
  const int dir  = w >> 5;
  const int j0   = (w & 31) * 16;
  const int tid  = (int)threadIdx.x;
  const int lane = tid & 63;
  const int wv   = tid >> 6;
  const int b    = tid >> 4;   // unique (b,sub) per thread
  const int sub  = tid & 15;
  const int len  = lengths[b];

  const float* bias = dir ? b_b : b_f;
  const float bi = bias[0 * HID + j0 + sub];
  const float bf = bias[1 * HID + j0 + sub];
  const float bg = bias[2 * HID + j0 + sub];
  const float bo = bias[3 * HID + j0 + sub];

  // ---- persistent W fragments, converted directly from fp32 inputs ----
  // col = wv*HID + j0 + (lane&15); k = kc*32 + (lane>>4)*8 + j
  s8v wfrag[32];
  {
    const float* Wi = dir ? Wi_b : Wi_f;
    const float* Wh = dir ? Wh_b : Wh_f;
    const int col = wv * HID + j0 + (lane & 15);
    const int kb  = (lane >> 4) * 8;
#pragma unroll
    for (int kc = 0; kc < 16; ++kc) {
      const float* src = Wi + (size_t)(kc * 32 + kb) * NCOL + col;
      s8v f;
#pragma unroll
      for (int j = 0; j < 8; ++j) f[j] = (short)f2b(src[(size_t)j * NCOL]);
      wfrag[kc] = f;
    }
#pragma unroll
    for (int kc = 0; kc < 16; ++kc) {
      const float* src = Wh + (size_t)(kc * 32 + kb) * NCOL + col;
      s8v f;
#pragma unroll
      for (int j = 0; j < 8; ++j) f[j] = (short)f2b(src[(size_t)j * NCOL]);
      wfrag[16 + kc] = f;
    }
  }

  float c_state = 0.f;
  const int arow = lane & 15;
  const int koff = (lane >> 4) * 8;

  for (int t = 0; t < T_SEQ; ++t) {
    const int tau = dir ? ((T_SEQ - 1 - t + len) & (T_SEQ - 1)) : t;

    // ---- stage A = [x_tau | h_{t-1}] as bf16 ----
    {
      const float* xrow = x + ((size_t)b * T_SEQ + tau) * DIM;
#pragma unroll
      for (int r = 0; r < 8; ++r) {
        const int k = sub * 4 + r * 64;
        f4v v = *(const f4v*)(xrow + k);
        h4v p;
        p[0] = f2b(v[0]); p[1] = f2b(v[1]); p[2] = f2b(v[2]); p[3] = f2b(v[3]);
        *(h4v*)&A[b][k] = p;
      }
    }
    if (t > 0) {
      const int taup = dir ? ((tau + 1) & (T_SEQ - 1)) : (t - 1);
      const float* hrow = out + ((size_t)b * T_SEQ + taup) * (2 * HID) + (size_t)dir * HID;
#pragma unroll
      for (int r = 0; r < 8; ++r) {
        const int k = sub * 4 + r * 64;
        f4v v = *(const f4v*)(hrow + k);
        h4v p;
        p[0] = f2b(v[0]); p[1] = f2b(v[1]); p[2] = f2b(v[2]); p[3] = f2b(v[3]);
        *(h4v*)&A[b][DIM + k] = p;
      }
    } else {
#pragma unroll
      for (int r = 0; r < 8; ++r) {
        const int k = sub * 4 + r * 64;
        h4v z = (h4v){0, 0, 0, 0};
        *(h4v*)&A[b][DIM + k] = z;
      }
    }
    __syncthreads();

    // ---- MFMA: 16x16 gate tile over K=1024 ----
    f4v acc0 = {0.f, 0.f, 0.f, 0.f}, acc1 = {0.f, 0.f, 0.f, 0.f};
    {
      const unsigned short* ap = &A[arow][koff];
#pragma unroll
      for (int kc = 0; kc < 32; kc += 2) {
        s8v a0 = *(const s8v*)(ap + kc * 32);
        s8v a1 = *(const s8v*)(ap + kc * 32 + 32);
        acc0 = mfma16(a0, wfrag[kc],     acc0);
        acc1 = mfma16(a1, wfrag[kc + 1], acc1);
      }
    }
    // C/D: col = lane&15, row = (lane>>4)*4 + r (row = batch)
#pragma unroll
    for (int r = 0; r < 4; ++r)
      glds[wv][(lane >> 4) * 4 + r][lane & 15] = acc0[r] + acc1[r];
    __syncthreads();

    // ---- fp32 gate math, one (b, j) per thread; h -> out directly ----
    {
      const float gi = glds[0][b][sub] + bi;
      const float gf = glds[1][b][sub] + bf;
      const float gg = glds[2][b][sub] + bg;
      const float go = glds[3][b][sub] + bo;
      const float si = 1.f / (1.f + __expf(-gi));
      const float sf = 1.f / (1.f + __expf(-gf));
      const float so = 1.f / (1.f + __expf(-go));
      const float tg = 1.f - 2.f / (1.f + __expf(2.f * gg));
      c_state = sf * c_state + si * tg;
      const float tc = 1.f - 2.f / (1.f + __expf(2.f * c_state));
      out[((size_t)b * T_SEQ + tau) * (2 * HID) + (size_t)dir * HID + j0 + sub] = so * tc;
    }

    // ---- device-scope step barrier (per direction, 32 wgs), leader spin ----
    __threadfence();     // release: flush h stores (wbl2) before signaling
    __syncthreads();
    if (tid == 0) {
      __hip_atomic_fetch_add(&ctr[dir], 1u, __ATOMIC_RELEASE, __HIP_MEMORY_SCOPE_AGENT);
      const unsigned tgt = 32u * (unsigned)(t + 1);
      while (__hip_atomic_load(&ctr[dir], __ATOMIC_ACQUIRE, __HIP_MEMORY_SCOPE_AGENT) < tgt)
        __builtin_amdgcn_s_sleep(4);
    }
    __syncthreads();
    __threadfence();     // acquire: invalidate stale L1/L2 before next h reads
  }
}

extern "C" void kernel_launch(void* const* d_in, const int* in_sizes, int n_in,
                              void* d_out, int out_size, void* d_ws, size_t ws_size,
                              hipStream_t stream) {
  const float* x    = (const float*)d_in[0];
  const int*   len  = (const int*)d_in[1];
  const float* Wi_f = (const float*)d_in[2];
  const float* Wh_f = (const float*)d_in[3];
  const float* b_f  = (const float*)d_in[4];
  const float* Wi_b = (const float*)d_in[5];
  const float* Wh_b = (const float*)d_in[6];
  const float* b_b  = (const float*)d_in[7];
  float* out = (float*)d_out;
  unsigned int* ctr = (unsigned int*)d_ws;   // 8 bytes used

  hipMemsetAsync(d_ws, 0, 256, stream);
  hipLaunchKernelGGL(lstm_persist, dim3(64), dim3(256), 0, stream,
                     x, len, Wi_f, Wh_f, b_f, Wi_b, Wh_b, b_b, ctr, out);
}

// Round 3
// 10893.521 us; speedup vs baseline: 2.8524x; 2.8524x over previous
//
#include <hip/hip_runtime.h>
#include <cstdint>
#include <cstddef>

#define T_SEQ 2048
#define BATCH 16
#define DIM   512
#define HID   512
#define KTOT  1024            // D + H
#define NCOL  2048            // 4H per direction
#define APAD  8
#define AROW  (KTOT + APAD)   // 1032 bf16 elems per A row -> 2-way-free LDS stride

typedef __attribute__((ext_vector_type(8))) short          s8v;
typedef __attribute__((ext_vector_type(4))) float          f4v;
typedef __attribute__((ext_vector_type(4))) unsigned short h4v;

__device__ __forceinline__ unsigned short f2b(float f) {
  unsigned u = __builtin_bit_cast(unsigned, f);
  return (unsigned short)((u + 0x7fffu + ((u >> 16) & 1u)) >> 16);  // RNE
}

// grid = 64 wgs x 256 thr. wg w: dir = w>>5, j-block = (w&31)*16.
// wave wv (0..3) owns gate wv's 16 cols; W fragments persist in registers.
// h exchanged through d_out with coherent (sc1) loads/stores — NO threadfence.
__global__ __launch_bounds__(256, 1)
void lstm_persist(const float* __restrict__ x, const int* __restrict__ lengths,
                  const float* __restrict__ Wi_f, const float* __restrict__ Wh_f,
                  const float* __restrict__ b_f,
                  const float* __restrict__ Wi_b, const float* __restrict__ Wh_b,
                  const float* __restrict__ b_b,
                  unsigned int* __restrict__ ctr,
                  float* __restrict__ out) {
  __shared__ unsigned short A[BATCH][AROW];   // [b][k] bf16
  __shared__ float glds[4][BATCH][16];        // gate exchange

  const int w    = (int)blockIdx.x;
  const int dir  = w >> 5;
  const int j0   = (w & 31) * 16;
  const int tid  = (int)threadIdx.x;
  const int lane = tid & 63;
  const int wv   = tid >> 6;
  const int b    = tid >> 4;   // unique (b,sub) per thread
  const int sub  = tid & 15;
  const int len  = lengths[b];

  const float* bias = dir ? b_b : b_f;
  const float bi = bias[0 * HID + j0 + sub];
  const float bf = bias[1 * HID + j0 + sub];
  const float bg = bias[2 * HID + j0 + sub];
  const float bo = bias[3 * HID + j0 + sub];

  // ---- persistent W fragments, fp32 -> bf16, col = wv*HID+j0+(lane&15) ----
  s8v wfrag[32];
  {
    const float* Wi = dir ? Wi_b : Wi_f;
    const float* Wh = dir ? Wh_b : Wh_f;
    const int col = wv * HID + j0 + (lane & 15);
    const int kb  = (lane >> 4) * 8;
#pragma unroll
    for (int kc = 0; kc < 16; ++kc) {
      const float* src = Wi + (size_t)(kc * 32 + kb) * NCOL + col;
      s8v f;
#pragma unroll
      for (int j = 0; j < 8; ++j) f[j] = (short)f2b(src[(size_t)j * NCOL]);
      wfrag[kc] = f;
    }
#pragma unroll
    for (int kc = 0; kc < 16; ++kc) {
      const float* src = Wh + (size_t)(kc * 32 + kb) * NCOL + col;
      s8v f;
#pragma unroll
      for (int j = 0; j < 8; ++j) f[j] = (short)f2b(src[(size_t)j * NCOL]);
      wfrag[16 + kc] = f;
    }
  }

  float c_state = 0.f;
  const int arow = lane & 15;
  const int koff = (lane >> 4) * 8;

  // ---- prologue: stage A = [x_tau(0) | h=0] ----
  {
    const int tau0 = dir ? ((T_SEQ - 1 + len) & (T_SEQ - 1)) : 0;
    const float* xrow = x + ((size_t)b * T_SEQ + tau0) * DIM;
#pragma unroll
    for (int r = 0; r < 8; ++r) {
      const int k = sub * 4 + r * 64;
      f4v v = *(const f4v*)(xrow + k);
      h4v p; p[0] = f2b(v[0]); p[1] = f2b(v[1]); p[2] = f2b(v[2]); p[3] = f2b(v[3]);
      *(h4v*)&A[b][k] = p;
      h4v z = (h4v){0, 0, 0, 0};
      *(h4v*)&A[b][DIM + k] = z;
    }
  }
  __syncthreads();

  for (int t = 0; t < T_SEQ; ++t) {
    const int tau = dir ? ((T_SEQ - 1 - t + len) & (T_SEQ - 1)) : t;

    // ---- MFMA: 16x16 gate tile over K=1024, 4 independent chains ----
    f4v acc0 = {0.f,0.f,0.f,0.f}, acc1 = {0.f,0.f,0.f,0.f};
    f4v acc2 = {0.f,0.f,0.f,0.f}, acc3 = {0.f,0.f,0.f,0.f};
    {
      const unsigned short* ap = &A[arow][koff];
#pragma unroll
      for (int kc = 0; kc < 32; kc += 4) {
        s8v a0 = *(const s8v*)(ap + (kc + 0) * 32);
        s8v a1 = *(const s8v*)(ap + (kc + 1) * 32);
        s8v a2 = *(const s8v*)(ap + (kc + 2) * 32);
        s8v a3 = *(const s8v*)(ap + (kc + 3) * 32);
        acc0 = __builtin_amdgcn_mfma_f32_16x16x32_bf16(a0, wfrag[kc + 0], acc0, 0, 0, 0);
        acc1 = __builtin_amdgcn_mfma_f32_16x16x32_bf16(a1, wfrag[kc + 1], acc1, 0, 0, 0);
        acc2 = __builtin_amdgcn_mfma_f32_16x16x32_bf16(a2, wfrag[kc + 2], acc2, 0, 0, 0);
        acc3 = __builtin_amdgcn_mfma_f32_16x16x32_bf16(a3, wfrag[kc + 3], acc3, 0, 0, 0);
      }
    }
#pragma unroll
    for (int r = 0; r < 4; ++r)
      glds[wv][(lane >> 4) * 4 + r][lane & 15] = (acc0[r] + acc1[r]) + (acc2[r] + acc3[r]);
    __syncthreads();   // A fully consumed; glds ready after this

    const bool notlast = (t + 1 < T_SEQ);

    // ---- prefetch x(t+1) early (hidden under gate math + barrier) ----
    f4v xv[8];
    if (notlast) {
      const int taun = dir ? ((T_SEQ - 2 - t + len) & (T_SEQ - 1)) : (t + 1);
      const float* xrow = x + ((size_t)b * T_SEQ + taun) * DIM;
#pragma unroll
      for (int r = 0; r < 8; ++r) xv[r] = *(const f4v*)(xrow + sub * 4 + r * 64);
    }

    // ---- fp32 gate math; h -> out via coherent store ----
    {
      const float gi = glds[0][b][sub] + bi;
      const float gf = glds[1][b][sub] + bf;
      const float gg = glds[2][b][sub] + bg;
      const float go = glds[3][b][sub] + bo;
      const float si = 1.f / (1.f + __expf(-gi));
      const float sf = 1.f / (1.f + __expf(-gf));
      const float so = 1.f / (1.f + __expf(-go));
      const float tg = 1.f - 2.f / (1.f + __expf(2.f * gg));
      c_state = sf * c_state + si * tg;
      const float tc = 1.f - 2.f / (1.f + __expf(2.f * c_state));
      const float h = so * tc;
      __hip_atomic_store(out + ((size_t)b * T_SEQ + tau) * (2 * HID) + (size_t)dir * HID + j0 + sub,
                         h, __ATOMIC_RELAXED, __HIP_MEMORY_SCOPE_AGENT);
    }

    if (notlast) {
      // ---- stage x(t+1) into A (x part) ----
#pragma unroll
      for (int r = 0; r < 8; ++r) {
        const int k = sub * 4 + r * 64;
        h4v p; p[0] = f2b(xv[r][0]); p[1] = f2b(xv[r][1]);
               p[2] = f2b(xv[r][2]); p[3] = f2b(xv[r][3]);
        *(h4v*)&A[b][k] = p;
      }

      // ---- fence-free device barrier (per direction, 32 wgs) ----
      asm volatile("s_waitcnt vmcnt(0)" ::: "memory");  // own h store at coherence point
      __syncthreads();                                   // all threads' stores done
      if (tid == 0) {
        __hip_atomic_fetch_add(&ctr[dir * 64], 1u, __ATOMIC_RELAXED, __HIP_MEMORY_SCOPE_AGENT);
        const unsigned tgt = 32u * (unsigned)(t + 1);
        while (__hip_atomic_load(&ctr[dir * 64], __ATOMIC_RELAXED, __HIP_MEMORY_SCOPE_AGENT) < tgt)
          __builtin_amdgcn_s_sleep(1);
      }
      __syncthreads();

      // ---- stage h(t) from out row tau via coherent u64 loads ----
      const float* hrow = out + ((size_t)b * T_SEQ + tau) * (2 * HID) + (size_t)dir * HID;
#pragma unroll
      for (int r = 0; r < 8; ++r) {
        const int k = sub * 4 + r * 64;
        const unsigned long long u0 =
            __hip_atomic_load((const unsigned long long*)(hrow + k), __ATOMIC_RELAXED, __HIP_MEMORY_SCOPE_AGENT);
        const unsigned long long u1 =
            __hip_atomic_load((const unsigned long long*)(hrow + k) + 1, __ATOMIC_RELAXED, __HIP_MEMORY_SCOPE_AGENT);
        const float f0 = __builtin_bit_cast(float, (unsigned)(u0 & 0xffffffffu));
        const float f1 = __builtin_bit_cast(float, (unsigned)(u0 >> 32));
        const float f2 = __builtin_bit_cast(float, (unsigned)(u1 & 0xffffffffu));
        const float f3 = __builtin_bit_cast(float, (unsigned)(u1 >> 32));
        h4v p; p[0] = f2b(f0); p[1] = f2b(f1); p[2] = f2b(f2); p[3] = f2b(f3);
        *(h4v*)&A[b][DIM + k] = p;
      }
      __syncthreads();
    }
  }
}

extern "C" void kernel_launch(void* const* d_in, const int* in_sizes, int n_in,
                              void* d_out, int out_size, void* d_ws, size_t ws_size,
                              hipStream_t stream) {
  const float* x    = (const float*)d_in[0];
  const int*   len  = (const int*)d_in[1];
  const float* Wi_f = (const float*)d_in[2];
  const float* Wh_f = (const float*)d_in[3];
  const float* b_f  = (const float*)d_in[4];
  const float* Wi_b = (const float*)d_in[5];
  const float* Wh_b = (const float*)d_in[6];
  const float* b_b  = (const float*)d_in[7];
  float* out = (float*)d_out;
  unsigned int* ctr = (unsigned int*)d_ws;   // ctr[0], ctr[64] (256B apart)

  hipMemsetAsync(d_ws, 0, 512, stream);
  hipLaunchKernelGGL(lstm_persist, dim3(64), dim3(256), 0, stream,
                     x, len, Wi_f, Wh_f, b_f, Wi_b, Wh_b, b_b, ctr, out);
}

// Round 4
// 6430.101 us; speedup vs baseline: 4.8323x; 1.6941x over previous
//
#include <hip/hip_runtime.h>
#include <cstdint>
#include <cstddef>

#define T_SEQ 2048
#define BATCH 16
#define DIM   512
#define HID   512
#define KTOT  1024            // D + H
#define NCOL  2048            // 4H per direction
#define APAD  8
#define AROW  (KTOT + APAD)   // 1032 bf16 elems per A row

typedef __attribute__((ext_vector_type(8))) short          s8v;
typedef __attribute__((ext_vector_type(4))) float          f4v;
typedef __attribute__((ext_vector_type(4))) unsigned short h4v;

__device__ __forceinline__ unsigned short f2b(float f) {
  unsigned u = __builtin_bit_cast(unsigned, f);
  return (unsigned short)((u + 0x7fffu + ((u >> 16) & 1u)) >> 16);  // RNE
}

// grid = 64 wgs x 256 thr. wg w: dir = w>>5, j-block = (w&31)*16.
// wave wv owns gate wv's 16 cols; W fragments persist in registers.
// h exchanged through d_out (coherent agent-scope ld/st). Step sync is a
// flag-array barrier: 32 parallel epoch stores + all-wave parallel poll
// (no atomic RMW serialization, no post-poll syncthreads).
__global__ __launch_bounds__(256, 1)
void lstm_persist(const float* __restrict__ x, const int* __restrict__ lengths,
                  const float* __restrict__ Wi_f, const float* __restrict__ Wh_f,
                  const float* __restrict__ b_f,
                  const float* __restrict__ Wi_b, const float* __restrict__ Wh_b,
                  const float* __restrict__ b_b,
                  unsigned int* __restrict__ flags,   // [(dir*32+g)*16], 64B apart
                  float* __restrict__ out) {
  __shared__ unsigned short A[BATCH][AROW];
  __shared__ float glds[4][BATCH][16];

  const int w    = (int)blockIdx.x;
  const int dir  = w >> 5;
  const int g    = w & 31;
  const int j0   = g * 16;
  const int tid  = (int)threadIdx.x;
  const int lane = tid & 63;
  const int wv   = tid >> 6;
  const int b    = tid >> 4;
  const int sub  = tid & 15;
  const int len  = lengths[b];

  const float* bias = dir ? b_b : b_f;
  const float bi = bias[0 * HID + j0 + sub];
  const float bf = bias[1 * HID + j0 + sub];
  const float bg = bias[2 * HID + j0 + sub];
  const float bo = bias[3 * HID + j0 + sub];

  // ---- persistent W fragments, fp32 -> bf16 ----
  s8v wfrag[32];
  {
    const float* Wi = dir ? Wi_b : Wi_f;
    const float* Wh = dir ? Wh_b : Wh_f;
    const int col = wv * HID + j0 + (lane & 15);
    const int kb  = (lane >> 4) * 8;
#pragma unroll
    for (int kc = 0; kc < 16; ++kc) {
      const float* src = Wi + (size_t)(kc * 32 + kb) * NCOL + col;
      s8v f;
#pragma unroll
      for (int j = 0; j < 8; ++j) f[j] = (short)f2b(src[(size_t)j * NCOL]);
      wfrag[kc] = f;
    }
#pragma unroll
    for (int kc = 0; kc < 16; ++kc) {
      const float* src = Wh + (size_t)(kc * 32 + kb) * NCOL + col;
      s8v f;
#pragma unroll
      for (int j = 0; j < 8; ++j) f[j] = (short)f2b(src[(size_t)j * NCOL]);
      wfrag[16 + kc] = f;
    }
  }

  float c_state = 0.f;
  const int arow = lane & 15;
  const int koff = (lane >> 4) * 8;
  unsigned int* myflag = flags + (size_t)(dir * 32 + g) * 16;
  unsigned int* pollbase = flags + (size_t)(dir * 32) * 16;

  // ---- prologue: stage A = [x_tau(0) | 0] ----
  {
    const int tau0 = dir ? ((T_SEQ - 1 + len) & (T_SEQ - 1)) : 0;
    const float* xrow = x + ((size_t)b * T_SEQ + tau0) * DIM;
#pragma unroll
    for (int r = 0; r < 8; ++r) {
      const int k = sub * 4 + r * 64;
      f4v v = *(const f4v*)(xrow + k);
      h4v p; p[0] = f2b(v[0]); p[1] = f2b(v[1]); p[2] = f2b(v[2]); p[3] = f2b(v[3]);
      *(h4v*)&A[b][k] = p;
      h4v z = (h4v){0, 0, 0, 0};
      *(h4v*)&A[b][DIM + k] = z;
    }
  }
  __syncthreads();

  for (int t = 0; t < T_SEQ; ++t) {
    const int tau = dir ? ((T_SEQ - 1 - t + len) & (T_SEQ - 1)) : t;
    const bool notlast = (t + 1 < T_SEQ);

    // ---- prefetch x(t+1) early: latency hides under MFMA + gates ----
    f4v xv[8];
    if (notlast) {
      const int taun = dir ? ((T_SEQ - 2 - t + len) & (T_SEQ - 1)) : (t + 1);
      const float* xrow = x + ((size_t)b * T_SEQ + taun) * DIM;
#pragma unroll
      for (int r = 0; r < 8; ++r) xv[r] = *(const f4v*)(xrow + sub * 4 + r * 64);
    }

    // ---- MFMA: 16x16 gate tile over K=1024, 4 chains ----
    f4v acc0 = {0.f,0.f,0.f,0.f}, acc1 = {0.f,0.f,0.f,0.f};
    f4v acc2 = {0.f,0.f,0.f,0.f}, acc3 = {0.f,0.f,0.f,0.f};
    {
      const unsigned short* ap = &A[arow][koff];
#pragma unroll
      for (int kc = 0; kc < 32; kc += 4) {
        s8v a0 = *(const s8v*)(ap + (kc + 0) * 32);
        s8v a1 = *(const s8v*)(ap + (kc + 1) * 32);
        s8v a2 = *(const s8v*)(ap + (kc + 2) * 32);
        s8v a3 = *(const s8v*)(ap + (kc + 3) * 32);
        acc0 = __builtin_amdgcn_mfma_f32_16x16x32_bf16(a0, wfrag[kc + 0], acc0, 0, 0, 0);
        acc1 = __builtin_amdgcn_mfma_f32_16x16x32_bf16(a1, wfrag[kc + 1], acc1, 0, 0, 0);
        acc2 = __builtin_amdgcn_mfma_f32_16x16x32_bf16(a2, wfrag[kc + 2], acc2, 0, 0, 0);
        acc3 = __builtin_amdgcn_mfma_f32_16x16x32_bf16(a3, wfrag[kc + 3], acc3, 0, 0, 0);
      }
    }
#pragma unroll
    for (int r = 0; r < 4; ++r)
      glds[wv][(lane >> 4) * 4 + r][lane & 15] = (acc0[r] + acc1[r]) + (acc2[r] + acc3[r]);
    __syncthreads();   // A consumed; glds ready

    // ---- fp32 gate math; h -> out via coherent store ----
    {
      const float gi = glds[0][b][sub] + bi;
      const float gf = glds[1][b][sub] + bf;
      const float gg = glds[2][b][sub] + bg;
      const float go = glds[3][b][sub] + bo;
      const float si = 1.f / (1.f + __expf(-gi));
      const float sf = 1.f / (1.f + __expf(-gf));
      const float so = 1.f / (1.f + __expf(-go));
      const float tg = 1.f - 2.f / (1.f + __expf(2.f * gg));
      c_state = sf * c_state + si * tg;
      const float tc = 1.f - 2.f / (1.f + __expf(2.f * c_state));
      const float h = so * tc;
      __hip_atomic_store(out + ((size_t)b * T_SEQ + tau) * (2 * HID) + (size_t)dir * HID + j0 + sub,
                         h, __ATOMIC_RELAXED, __HIP_MEMORY_SCOPE_AGENT);
    }

    if (notlast) {
      // ---- stage x(t+1) into A (x part) ----
#pragma unroll
      for (int r = 0; r < 8; ++r) {
        const int k = sub * 4 + r * 64;
        h4v p; p[0] = f2b(xv[r][0]); p[1] = f2b(xv[r][1]);
               p[2] = f2b(xv[r][2]); p[3] = f2b(xv[r][3]);
        *(h4v*)&A[b][k] = p;
      }

      // ---- flag-array device barrier (per direction, 32 wgs) ----
      asm volatile("s_waitcnt vmcnt(0)" ::: "memory");  // h store at coherence point
      __syncthreads();                                   // all threads drained
      if (tid == 0)
        __hip_atomic_store(myflag, (unsigned)(t + 1), __ATOMIC_RELAXED, __HIP_MEMORY_SCOPE_AGENT);
      {
        const unsigned tgt = (unsigned)(t + 1);
        while (true) {
          unsigned v = __hip_atomic_load(pollbase + (size_t)(lane & 31) * 16,
                                         __ATOMIC_RELAXED, __HIP_MEMORY_SCOPE_AGENT);
          if (__all(v >= tgt)) break;
          __builtin_amdgcn_s_sleep(1);
        }
      }

      // ---- stage h(t): issue all coherent loads, then convert ----
      const float* hrow = out + ((size_t)b * T_SEQ + tau) * (2 * HID) + (size_t)dir * HID;
      unsigned long long hu[16];
#pragma unroll
      for (int r = 0; r < 8; ++r) {
        const int k = sub * 4 + r * 64;
        hu[2 * r]     = __hip_atomic_load((const unsigned long long*)(hrow + k),
                                          __ATOMIC_RELAXED, __HIP_MEMORY_SCOPE_AGENT);
        hu[2 * r + 1] = __hip_atomic_load((const unsigned long long*)(hrow + k) + 1,
                                          __ATOMIC_RELAXED, __HIP_MEMORY_SCOPE_AGENT);
      }
#pragma unroll
      for (int r = 0; r < 8; ++r) {
        const int k = sub * 4 + r * 64;
        const float f0 = __builtin_bit_cast(float, (unsigned)(hu[2 * r] & 0xffffffffu));
        const float f1 = __builtin_bit_cast(float, (unsigned)(hu[2 * r] >> 32));
        const float f2 = __builtin_bit_cast(float, (unsigned)(hu[2 * r + 1] & 0xffffffffu));
        const float f3 = __builtin_bit_cast(float, (unsigned)(hu[2 * r + 1] >> 32));
        h4v p; p[0] = f2b(f0); p[1] = f2b(f1); p[2] = f2b(f2); p[3] = f2b(f3);
        *(h4v*)&A[b][DIM + k] = p;
      }
      __syncthreads();   // A[h] ready for next MFMA
    }
  }
}

extern "C" void kernel_launch(void* const* d_in, const int* in_sizes, int n_in,
                              void* d_out, int out_size, void* d_ws, size_t ws_size,
                              hipStream_t stream) {
  const float* x    = (const float*)d_in[0];
  const int*   len  = (const int*)d_in[1];
  const float* Wi_f = (const float*)d_in[2];
  const float* Wh_f = (const float*)d_in[3];
  const float* b_f  = (const float*)d_in[4];
  const float* Wi_b = (const float*)d_in[5];
  const float* Wh_b = (const float*)d_in[6];
  const float* b_b  = (const float*)d_in[7];
  float* out = (float*)d_out;
  unsigned int* flags = (unsigned int*)d_ws;   // 2*32 flags, 64B apart = 4KB

  hipMemsetAsync(d_ws, 0, 4096, stream);
  hipLaunchKernelGGL(lstm_persist, dim3(64), dim3(256), 0, stream,
                     x, len, Wi_f, Wh_f, b_f, Wi_b, Wh_b, b_b, flags, out);
}

// Round 5
// 5721.519 us; speedup vs baseline: 5.4308x; 1.1238x over previous
//
#include <hip/hip_runtime.h>
#include <cstdint>
#include <cstddef>

#define T_SEQ 2048
#define BATCH 16
#define DIM   512
#define HID   512
#define KTOT  1024            // D + H
#define NCOL  2048            // 4H per direction
#define APAD  8
#define AROW  (KTOT + APAD)   // 1032 bf16 elems per A row

typedef __attribute__((ext_vector_type(8))) short          s8v;
typedef __attribute__((ext_vector_type(4))) float          f4v;
typedef __attribute__((ext_vector_type(4))) unsigned short h4v;

// hx exchange buffer: u32 = (bf16(h) << 16) | epoch, [dir][slot][b][j]
#define HXIDX(d, s, b, j) (((((d) * 2 + (s)) * BATCH + (b)) * HID) + (j))

__device__ __forceinline__ unsigned short f2b(float f) {
  unsigned u = __builtin_bit_cast(unsigned, f);
  return (unsigned short)((u + 0x7fffu + ((u >> 16) & 1u)) >> 16);  // RNE
}

// grid = 64 wgs x 256 thr. wg w: dir = w>>5, j-block = (w&31)*16.
// Wave wv owns gate wv's 16 cols; W fragments persist in registers.
// NO barrier: h values are self-validating (epoch-tagged bf16 in d_ws).
// Consumers poll exactly the data they need; wgs free-run on dataflow.
__global__ __launch_bounds__(256, 1)
void lstm_persist(const float* __restrict__ x, const int* __restrict__ lengths,
                  const float* __restrict__ Wi_f, const float* __restrict__ Wh_f,
                  const float* __restrict__ b_f,
                  const float* __restrict__ Wi_b, const float* __restrict__ Wh_b,
                  const float* __restrict__ b_b,
                  unsigned int* __restrict__ hx,
                  float* __restrict__ out) {
  __shared__ unsigned short A[BATCH][AROW];
  __shared__ float glds[4][BATCH][16];

  const int w    = (int)blockIdx.x;
  const int dir  = w >> 5;
  const int g    = w & 31;
  const int j0   = g * 16;
  const int tid  = (int)threadIdx.x;
  const int lane = tid & 63;
  const int wv   = tid >> 6;
  const int b    = tid >> 4;
  const int sub  = tid & 15;
  const int len  = lengths[b];

  const float* bias = dir ? b_b : b_f;
  const float bi = bias[0 * HID + j0 + sub];
  const float bf = bias[1 * HID + j0 + sub];
  const float bg = bias[2 * HID + j0 + sub];
  const float bo = bias[3 * HID + j0 + sub];

  // ---- persistent W fragments, fp32 -> bf16 ----
  s8v wfrag[32];
  {
    const float* Wi = dir ? Wi_b : Wi_f;
    const float* Wh = dir ? Wh_b : Wh_f;
    const int col = wv * HID + j0 + (lane & 15);
    const int kb  = (lane >> 4) * 8;
#pragma unroll
    for (int kc = 0; kc < 16; ++kc) {
      const float* src = Wi + (size_t)(kc * 32 + kb) * NCOL + col;
      s8v f;
#pragma unroll
      for (int j = 0; j < 8; ++j) f[j] = (short)f2b(src[(size_t)j * NCOL]);
      wfrag[kc] = f;
    }
#pragma unroll
    for (int kc = 0; kc < 16; ++kc) {
      const float* src = Wh + (size_t)(kc * 32 + kb) * NCOL + col;
      s8v f;
#pragma unroll
      for (int j = 0; j < 8; ++j) f[j] = (short)f2b(src[(size_t)j * NCOL]);
      wfrag[16 + kc] = f;
    }
  }

  float c_state = 0.f;
  const int arow = lane & 15;
  const int koff = (lane >> 4) * 8;

  // ---- prologue: stage A = [x_tau(0) | 0] ----
  {
    const int tau0 = dir ? ((T_SEQ - 1 + len) & (T_SEQ - 1)) : 0;
    const float* xrow = x + ((size_t)b * T_SEQ + tau0) * DIM;
#pragma unroll
    for (int r = 0; r < 8; ++r) {
      const int k = sub * 4 + r * 64;
      f4v v = *(const f4v*)(xrow + k);
      h4v p; p[0] = f2b(v[0]); p[1] = f2b(v[1]); p[2] = f2b(v[2]); p[3] = f2b(v[3]);
      *(h4v*)&A[b][k] = p;
      h4v z = (h4v){0, 0, 0, 0};
      *(h4v*)&A[b][DIM + k] = z;
    }
  }
  __syncthreads();

  for (int t = 0; t < T_SEQ; ++t) {
    const int tau = dir ? ((T_SEQ - 1 - t + len) & (T_SEQ - 1)) : t;
    const bool notlast = (t + 1 < T_SEQ);
    const unsigned e = (unsigned)(t + 1);   // epoch published this step

    // ---- prefetch x(t+1): latency hides under MFMA + gates ----
    f4v xv[8];
    if (notlast) {
      const int taun = dir ? ((T_SEQ - 2 - t + len) & (T_SEQ - 1)) : (t + 1);
      const float* xrow = x + ((size_t)b * T_SEQ + taun) * DIM;
#pragma unroll
      for (int r = 0; r < 8; ++r) xv[r] = *(const f4v*)(xrow + sub * 4 + r * 64);
    }

    // ---- MFMA: 16x16 gate tile over K=1024, 4 chains ----
    f4v acc0 = {0.f,0.f,0.f,0.f}, acc1 = {0.f,0.f,0.f,0.f};
    f4v acc2 = {0.f,0.f,0.f,0.f}, acc3 = {0.f,0.f,0.f,0.f};
    {
      const unsigned short* ap = &A[arow][koff];
#pragma unroll
      for (int kc = 0; kc < 32; kc += 4) {
        s8v a0 = *(const s8v*)(ap + (kc + 0) * 32);
        s8v a1 = *(const s8v*)(ap + (kc + 1) * 32);
        s8v a2 = *(const s8v*)(ap + (kc + 2) * 32);
        s8v a3 = *(const s8v*)(ap + (kc + 3) * 32);
        acc0 = __builtin_amdgcn_mfma_f32_16x16x32_bf16(a0, wfrag[kc + 0], acc0, 0, 0, 0);
        acc1 = __builtin_amdgcn_mfma_f32_16x16x32_bf16(a1, wfrag[kc + 1], acc1, 0, 0, 0);
        acc2 = __builtin_amdgcn_mfma_f32_16x16x32_bf16(a2, wfrag[kc + 2], acc2, 0, 0, 0);
        acc3 = __builtin_amdgcn_mfma_f32_16x16x32_bf16(a3, wfrag[kc + 3], acc3, 0, 0, 0);
      }
    }
#pragma unroll
    for (int r = 0; r < 4; ++r)
      glds[wv][(lane >> 4) * 4 + r][lane & 15] = (acc0[r] + acc1[r]) + (acc2[r] + acc3[r]);
    __syncthreads();   // A consumed; glds ready

    // ---- fp32 gate math; publish tagged h first, then plain out store ----
    {
      const float gi = glds[0][b][sub] + bi;
      const float gf = glds[1][b][sub] + bf;
      const float gg = glds[2][b][sub] + bg;
      const float go = glds[3][b][sub] + bo;
      const float si = 1.f / (1.f + __expf(-gi));
      const float sf = 1.f / (1.f + __expf(-gf));
      const float so = 1.f / (1.f + __expf(-go));
      const float tg = 1.f - 2.f / (1.f + __expf(2.f * gg));
      c_state = sf * c_state + si * tg;
      const float tc = 1.f - 2.f / (1.f + __expf(2.f * c_state));
      const float h = so * tc;
      if (notlast) {
        const unsigned tagged = ((unsigned)f2b(h) << 16) | e;
        __hip_atomic_store(&hx[HXIDX(dir, e & 1, b, j0 + sub)], tagged,
                           __ATOMIC_RELAXED, __HIP_MEMORY_SCOPE_AGENT);
      }
      out[((size_t)b * T_SEQ + tau) * (2 * HID) + (size_t)dir * HID + j0 + sub] = h;
    }

    if (notlast) {
      // ---- stage x(t+1) into A (x part; A is free after the sync above) ----
#pragma unroll
      for (int r = 0; r < 8; ++r) {
        const int k = sub * 4 + r * 64;
        h4v p; p[0] = f2b(xv[r][0]); p[1] = f2b(xv[r][1]);
               p[2] = f2b(xv[r][2]); p[3] = f2b(xv[r][3]);
        *(h4v*)&A[b][k] = p;
      }

      // ---- poll h(t): data-as-signal, values land in registers ----
      const unsigned* hrow = hx + HXIDX(dir, e & 1, b, 0);
      const unsigned long long msk = 0x0000FFFF0000FFFFULL;
      const unsigned long long pat = ((unsigned long long)e << 32) | e;
      unsigned long long hu[16];
      while (true) {
        bool ok = true;
#pragma unroll
        for (int r = 0; r < 8; ++r) {
          const int k = sub * 4 + r * 64;
          hu[2 * r]     = __hip_atomic_load((const unsigned long long*)(hrow + k),
                                            __ATOMIC_RELAXED, __HIP_MEMORY_SCOPE_AGENT);
          hu[2 * r + 1] = __hip_atomic_load((const unsigned long long*)(hrow + k) + 1,
                                            __ATOMIC_RELAXED, __HIP_MEMORY_SCOPE_AGENT);
          ok &= ((hu[2 * r] & msk) == pat) & ((hu[2 * r + 1] & msk) == pat);
        }
        if (ok) break;
        __builtin_amdgcn_s_sleep(1);
      }
#pragma unroll
      for (int r = 0; r < 8; ++r) {
        const int k = sub * 4 + r * 64;
        h4v p;
        p[0] = (unsigned short)(hu[2 * r] >> 16);
        p[1] = (unsigned short)(hu[2 * r] >> 48);
        p[2] = (unsigned short)(hu[2 * r + 1] >> 16);
        p[3] = (unsigned short)(hu[2 * r + 1] >> 48);
        *(h4v*)&A[b][DIM + k] = p;
      }
      __syncthreads();   // A ready for next MFMA
    }
  }
}

extern "C" void kernel_launch(void* const* d_in, const int* in_sizes, int n_in,
                              void* d_out, int out_size, void* d_ws, size_t ws_size,
                              hipStream_t stream) {
  const float* x    = (const float*)d_in[0];
  const int*   len  = (const int*)d_in[1];
  const float* Wi_f = (const float*)d_in[2];
  const float* Wh_f = (const float*)d_in[3];
  const float* b_f  = (const float*)d_in[4];
  const float* Wi_b = (const float*)d_in[5];
  const float* Wh_b = (const float*)d_in[6];
  const float* b_b  = (const float*)d_in[7];
  float* out = (float*)d_out;
  unsigned int* hx = (unsigned int*)d_ws;   // [2][2][16][512] u32 = 128 KB

  hipMemsetAsync(d_ws, 0, (size_t)2 * 2 * BATCH * HID * 4, stream);
  hipLaunchKernelGGL(lstm_persist, dim3(64), dim3(256), 0, stream,
                     x, len, Wi_f, Wh_f, b_f, Wi_b, Wh_b, b_b, hx, out);
}